// Round 11
// baseline (121.723 us; speedup 1.0000x reference)
//
#include <hip/hip_runtime.h>
#include <hip/hip_bf16.h>

#define E_EDGES 300000
#define N_NODES 50000
#define BE 512              // edges per block (4 waves x 128 edges)
#define NT 256
#define KC 256              // K-depth per chunk
#define CHUNK_BYTES 16384   // 32 v * 256 k * 2B
#define CPB 8               // chunks per block (K split in 2)
#define BIAS_OFF 262144     // b2 image (2 KB)
#define W1PK_OFF 264192     // W1 dup-f16 image (3 KB)
#define B1PK_OFF 267264     // b1 dup-f16 image (512 B)

typedef _Float16 h2 __attribute__((ext_vector_type(2)));
typedef _Float16 h8 __attribute__((ext_vector_type(8)));
typedef float f32x16 __attribute__((ext_vector_type(16)));

static __device__ __forceinline__ unsigned short f2h(float f) {
  _Float16 h = (_Float16)f;
  return __builtin_bit_cast(unsigned short, h);
}
static __device__ __forceinline__ h2 cvt2(float a, float b) {
  auto r = __builtin_amdgcn_cvt_pkrtz(a, b);
  return __builtin_bit_cast(h2, r);
}
static __device__ __forceinline__ h2 bcu(unsigned u) { return __builtin_bit_cast(h2, u); }
static __device__ __forceinline__ h2 dup_lo(unsigned u) {
  h2 p = bcu(u); return (h2){p[0], p[0]};
}
static __device__ __forceinline__ h2 dup_hi(unsigned u) {
  h2 p = bcu(u); return (h2){p[1], p[1]};
}
// A-fragment = hd (broadcast h) * 4 packed x pairs -> 4 v_pk_mul_f16
static __device__ __forceinline__ h8 mk4(h2 hd, const h2* p) {
  h2 m0 = hd * p[0], m1 = hd * p[1], m2 = hd * p[2], m3 = hd * p[3];
  return (h8){m0[0], m0[1], m1[0], m1[1], m2[0], m2[1], m3[0], m3[1]};
}
static __device__ __forceinline__ h8 pk4(const h2* p) {
  return (h8){p[0][0], p[0][1], p[1][0], p[1][1], p[2][0], p[2][1], p[3][0], p[3][1]};
}

// ---------------------------------------------------------------------------
// Prep: W2 (flat (4096,32) row-major) -> f16, transposed [v][k] per 256-deep
// chunk, XOR-swizzled ((v&31)<<4, bijective within 512B rows), linear images
// in ws. b2 -> [v][w] f16 image. W1/b1 -> duplicated-f16 u32 images.
// ---------------------------------------------------------------------------
__global__ void prep_w2t(const float* __restrict__ W2, const float* __restrict__ b2,
                         const float* __restrict__ W1, const float* __restrict__ b1,
                         char* __restrict__ ws) {
  int tid = blockIdx.x * 256 + threadIdx.x;
  if (tid < 65536) {                  // 16 chunks * 32 v * 128 k-pairs
    int c   = tid >> 12;
    int rem = tid & 4095;
    int v   = rem >> 7;
    int kp  = rem & 127;
    int kg2 = c * KC + kp * 2;
    unsigned u = (unsigned)f2h(W2[(size_t)kg2 * 32 + v]) |
                 ((unsigned)f2h(W2[(size_t)(kg2 + 1) * 32 + v]) << 16);
    int off = c * CHUNK_BYTES + v * 512 + ((kp * 4) ^ ((v & 31) << 4));
    *(unsigned*)(ws + off) = u;
  } else if (tid < 66048) {           // bias b2: 32 v * 16 w-pairs
    int i  = tid - 65536;
    int v  = i & 31;
    int wp = i >> 5;
    int w  = wp * 2;
    unsigned u = (unsigned)f2h(b2[w * 32 + v]) |
                 ((unsigned)f2h(b2[(w + 1) * 32 + v]) << 16);
    *(unsigned*)(ws + BIAS_OFF + v * 64 + wp * 4) = u;
  } else if (tid < 66816) {           // W1 dup image: 6*128
    int i = tid - 66048;
    unsigned short s = f2h(W1[i]);
    *(unsigned*)(ws + W1PK_OFF + i * 4) = (unsigned)s | ((unsigned)s << 16);
  } else if (tid < 66944) {           // b1 dup image: 128
    int i = tid - 66816;
    unsigned short s = f2h(b1[i]);
    *(unsigned*)(ws + B1PK_OFF + i * 4) = (unsigned)s | ((unsigned)s << 16);
  }
}

// ---------------------------------------------------------------------------
// Fused main: 4 waves x 128 edges (4 acc chains/wave), K split across
// blockIdx.y (8 chunks each, merged via atomic scatter). Packed-f16 h
// (lane owns 2 edges; 2 shfls/kq serve all 4 accs) -> pk_mul A-frags ->
// f16 MFMA vs LDS dbuf W2 chunk -> bias (kh==0) -> atomic scatter.
// ---------------------------------------------------------------------------
__launch_bounds__(NT, 3)
__global__ void nnconv_main(const float* __restrict__ x,
                            const int* __restrict__ senders,
                            const int* __restrict__ receivers,
                            const float* __restrict__ edge_attr,
                            const char* __restrict__ ws,
                            float* __restrict__ out) {
  __shared__ __align__(16) char w2t[2][CHUNK_BYTES];
  __shared__ int rcv_lds[BE];

  const int t    = threadIdx.x;
  const int wid  = t >> 6;
  const int lane = t & 63;
  const int col  = lane & 31;
  const int hi   = lane >> 5;
  const int E0   = blockIdx.x * BE;
  const int kh   = blockIdx.y;
  const int c0   = kh * CPB;

  // ---- issue async stage of first chunk
#pragma unroll
  for (int it = 0; it < 4; ++it)
    __builtin_amdgcn_global_load_lds(
        (const __attribute__((address_space(1))) void*)(ws + c0 * CHUNK_BYTES + it * 4096 + t * 16),
        (__attribute__((address_space(3))) void*)(&w2t[0][0] + it * 4096 + t * 16), 16, 0, 0);

#pragma unroll
  for (int i = t; i < BE; i += NT)
    rcv_lds[i] = (E0 + i < E_EDGES) ? receivers[E0 + i] : -1;

  const int wb = wid * 128;           // wave-local edge base

  // ---- h-owned edges for this lane: lo = wb+lane, hi = wb+64+lane
  const int geL = min(E0 + wb + lane, E_EDGES - 1);
  const int geH = min(E0 + wb + 64 + lane, E_EDGES - 1);
  h2 ea2[6];
  {
    const float2* p0 = (const float2*)(edge_attr + (size_t)geL * 6);
    const float2* p1 = (const float2*)(edge_attr + (size_t)geH * 6);
    const float2 a0 = p0[0], a1 = p0[1], a2 = p0[2];
    const float2 c0f = p1[0], c1f = p1[1], c2f = p1[2];
    ea2[0] = cvt2(a0.x, c0f.x); ea2[1] = cvt2(a0.y, c0f.y);
    ea2[2] = cvt2(a1.x, c1f.x); ea2[3] = cvt2(a1.y, c1f.y);
    ea2[4] = cvt2(a2.x, c2f.x); ea2[5] = cvt2(a2.y, c2f.y);
  }

  // ---- gather x_j slices for the 4 acc rows this lane touches
  h2 xA[4][4], xB[4][4];
#pragma unroll
  for (int g = 0; g < 4; ++g) {
    const int ge = min(E0 + wb + g * 32 + col, E_EDGES - 1);
    const float* row = x + (size_t)senders[ge] * 32;
    float4 fa = *(const float4*)(row + hi * 8);
    float4 fb = *(const float4*)(row + hi * 8 + 4);
    xA[g][0] = cvt2(fa.x, fa.y); xA[g][1] = cvt2(fa.z, fa.w);
    xA[g][2] = cvt2(fb.x, fb.y); xA[g][3] = cvt2(fb.z, fb.w);
    fa = *(const float4*)(row + 16 + hi * 8);
    fb = *(const float4*)(row + 16 + hi * 8 + 4);
    xB[g][0] = cvt2(fa.x, fa.y); xB[g][1] = cvt2(fa.z, fa.w);
    xB[g][2] = cvt2(fb.x, fb.y); xB[g][3] = cvt2(fb.z, fb.w);
  }

  const unsigned* w1p = (const unsigned*)(ws + W1PK_OFF);
  const unsigned* b1p = (const unsigned*)(ws + B1PK_OFF);

  __syncthreads();   // rcv + first chunk ready

  f32x16 acc0 = {}, acc1 = {}, acc2 = {}, acc3 = {};
  const int swB = (col & 31) << 4;
  int buf = 0;

#pragma unroll 1
  for (int ci = 0; ci < CPB; ++ci) {
    const int c = c0 + ci;
    if (ci + 1 < CPB) {   // prefetch next chunk into other buffer
      const char* g = ws + (c + 1) * CHUNK_BYTES;
      char* l = &w2t[buf ^ 1][0];
#pragma unroll
      for (int it = 0; it < 4; ++it)
        __builtin_amdgcn_global_load_lds(
            (const __attribute__((address_space(1))) void*)(g + it * 4096 + t * 16),
            (__attribute__((address_space(3))) void*)(l + it * 4096 + t * 16), 16, 0, 0);
    }

    // ---- h for hidden units c*8..c*8+7, both owned edges packed
    unsigned hp[8];
    {
      h2 hv[8];
      const uint4* bq = (const uint4*)(b1p + c * 8);
      const uint4 b0 = bq[0], b4 = bq[1];
      hv[0] = bcu(b0.x); hv[1] = bcu(b0.y); hv[2] = bcu(b0.z); hv[3] = bcu(b0.w);
      hv[4] = bcu(b4.x); hv[5] = bcu(b4.y); hv[6] = bcu(b4.z); hv[7] = bcu(b4.w);
#pragma unroll
      for (int d = 0; d < 6; ++d) {
        const uint4* wq = (const uint4*)(w1p + d * 128 + c * 8);
        const uint4 w0 = wq[0], w4 = wq[1];
        hv[0] += ea2[d] * bcu(w0.x); hv[1] += ea2[d] * bcu(w0.y);
        hv[2] += ea2[d] * bcu(w0.z); hv[3] += ea2[d] * bcu(w0.w);
        hv[4] += ea2[d] * bcu(w4.x); hv[5] += ea2[d] * bcu(w4.y);
        hv[6] += ea2[d] * bcu(w4.z); hv[7] += ea2[d] * bcu(w4.w);
      }
#pragma unroll
      for (int kq = 0; kq < 8; ++kq)
        hp[kq] = __builtin_bit_cast(unsigned,
                   __builtin_elementwise_max(hv[kq], (h2)(_Float16)0));
    }

    // ---- 16 K-steps, 4 MFMAs each (4 independent acc chains)
    const char* Bb = &w2t[buf][0] + col * 512;
    h2 hd0, hd1, hd2, hd3;
#pragma unroll
    for (int s = 0; s < 16; ++s) {
      const int kq = s >> 1;
      if ((s & 1) == 0) {
        const unsigned u0 = __shfl(hp[kq], col);
        const unsigned u1 = __shfl(hp[kq], col + 32);
        hd0 = dup_lo(u0);   // edge wb + col       (owner lane col, lo)
        hd1 = dup_lo(u1);   // edge wb + 32 + col  (owner lane 32+col, lo)
        hd2 = dup_hi(u0);   // edge wb + 64 + col  (owner lane col, hi)
        hd3 = dup_hi(u1);   // edge wb + 96 + col  (owner lane 32+col, hi)
      }
      const h8 B = *(const h8*)(Bb + ((s * 32 + hi * 16) ^ swB));
      if (s & 1) {
        acc0 = __builtin_amdgcn_mfma_f32_32x32x16_f16(mk4(hd0, xB[0]), B, acc0, 0, 0, 0);
        acc1 = __builtin_amdgcn_mfma_f32_32x32x16_f16(mk4(hd1, xB[1]), B, acc1, 0, 0, 0);
        acc2 = __builtin_amdgcn_mfma_f32_32x32x16_f16(mk4(hd2, xB[2]), B, acc2, 0, 0, 0);
        acc3 = __builtin_amdgcn_mfma_f32_32x32x16_f16(mk4(hd3, xB[3]), B, acc3, 0, 0, 0);
      } else {
        acc0 = __builtin_amdgcn_mfma_f32_32x32x16_f16(mk4(hd0, xA[0]), B, acc0, 0, 0, 0);
        acc1 = __builtin_amdgcn_mfma_f32_32x32x16_f16(mk4(hd1, xA[1]), B, acc1, 0, 0, 0);
        acc2 = __builtin_amdgcn_mfma_f32_32x32x16_f16(mk4(hd2, xA[2]), B, acc2, 0, 0, 0);
        acc3 = __builtin_amdgcn_mfma_f32_32x32x16_f16(mk4(hd3, xA[3]), B, acc3, 0, 0, 0);
      }
    }
    __syncthreads();   // drains prefetch + protects buffer reuse
    buf ^= 1;
  }

  // ---- bias: only the kh==0 half adds it (h == 1 MFMAs)
  if (kh == 0) {
    const char* bb = ws + BIAS_OFF + col * 64;
    const h8 B0 = *(const h8*)(bb + hi * 16);
    const h8 B1 = *(const h8*)(bb + 32 + hi * 16);
    acc0 = __builtin_amdgcn_mfma_f32_32x32x16_f16(pk4(xA[0]), B0, acc0, 0, 0, 0);
    acc1 = __builtin_amdgcn_mfma_f32_32x32x16_f16(pk4(xA[1]), B0, acc1, 0, 0, 0);
    acc2 = __builtin_amdgcn_mfma_f32_32x32x16_f16(pk4(xA[2]), B0, acc2, 0, 0, 0);
    acc3 = __builtin_amdgcn_mfma_f32_32x32x16_f16(pk4(xA[3]), B0, acc3, 0, 0, 0);
    acc0 = __builtin_amdgcn_mfma_f32_32x32x16_f16(pk4(xB[0]), B1, acc0, 0, 0, 0);
    acc1 = __builtin_amdgcn_mfma_f32_32x32x16_f16(pk4(xB[1]), B1, acc1, 0, 0, 0);
    acc2 = __builtin_amdgcn_mfma_f32_32x32x16_f16(pk4(xB[2]), B1, acc2, 0, 0, 0);
    acc3 = __builtin_amdgcn_mfma_f32_32x32x16_f16(pk4(xB[3]), B1, acc3, 0, 0, 0);
  }

  // ---- scatter: C/D layout col=lane&31, row=(r&3)+8*(r>>2)+4*hi
#pragma unroll
  for (int r = 0; r < 16; ++r) {
    const int row = (r & 3) + 8 * (r >> 2) + 4 * hi;
    const int r0 = rcv_lds[wb + row];
    if (r0 >= 0) atomicAdd(out + (size_t)r0 * 32 + col, acc0[r]);
    const int r1 = rcv_lds[wb + 32 + row];
    if (r1 >= 0) atomicAdd(out + (size_t)r1 * 32 + col, acc1[r]);
    const int r2 = rcv_lds[wb + 64 + row];
    if (r2 >= 0) atomicAdd(out + (size_t)r2 * 32 + col, acc2[r]);
    const int r3 = rcv_lds[wb + 96 + row];
    if (r3 >= 0) atomicAdd(out + (size_t)r3 * 32 + col, acc3[r]);
  }
}

extern "C" void kernel_launch(void* const* d_in, const int* in_sizes, int n_in,
                              void* d_out, int out_size, void* d_ws, size_t ws_size,
                              hipStream_t stream) {
  const float* x         = (const float*)d_in[0];
  const int*   senders   = (const int*)d_in[1];
  const int*   receivers = (const int*)d_in[2];
  const float* edge_attr = (const float*)d_in[3];
  const float* W1        = (const float*)d_in[4];
  const float* b1        = (const float*)d_in[5];
  const float* W2        = (const float*)d_in[6];
  const float* b2        = (const float*)d_in[7];
  float* out = (float*)d_out;
  char*  ws  = (char*)d_ws;

  (void)hipMemsetAsync(out, 0, (size_t)N_NODES * 32 * sizeof(float), stream);
  prep_w2t<<<262, 256, 0, stream>>>(W2, b2, W1, b1, ws);
  dim3 grid((E_EDGES + BE - 1) / BE, 2);
  nnconv_main<<<grid, NT, 0, stream>>>(
      x, senders, receivers, edge_attr, ws, out);
}